// Round 1
// baseline (548.175 us; speedup 1.0000x reference)
//
#include <hip/hip_runtime.h>
#include <math.h>

#define FIN 128
#define HID 16
#define NC 8

// ---------------------------------------------------------------------------
// dtype probe: decide whether edge_index is int64 or int32 (device-side).
// If int64, first 16 values as int64 are all in [0,N). If int32, each int64
// read combines two random indices -> value >= N with prob ~(1 - 1e-5).
// ---------------------------------------------------------------------------
__global__ void detect64_kernel(const void* __restrict__ ei, int E, int N,
                                int* __restrict__ flag) {
    if (blockIdx.x == 0 && threadIdx.x == 0) {
        const long long* p = (const long long*)ei;
        int ok = 1;
        for (int i = 0; i < 16; ++i) {
            long long v = p[i];
            if (v < 0 || v >= (long long)N) { ok = 0; break; }
        }
        *flag = ok;
    }
}

__device__ __forceinline__ int edge_at(const void* __restrict__ ei, long long pos, int is64) {
    return is64 ? (int)((const long long*)ei)[pos] : ((const int*)ei)[pos];
}

// deg[n] = 1 (self loop)
__global__ void init_deg_kernel(float* __restrict__ deg, int N) {
    int n = blockIdx.x * blockDim.x + threadIdx.x;
    if (n < N) deg[n] = 1.0f;
}

// deg[dst[e]] += 1
__global__ void deg_kernel(const void* __restrict__ ei, int E,
                           const int* __restrict__ flag, float* __restrict__ deg) {
    int is64 = *flag;
    for (int e = blockIdx.x * blockDim.x + threadIdx.x; e < E;
         e += gridDim.x * blockDim.x) {
        int d = edge_at(ei, (long long)E + e, is64);
        atomicAdd(&deg[d], 1.0f);
    }
}

// in place: deg -> rsqrt(deg)
__global__ void dinv_kernel(float* __restrict__ deg, int N) {
    int n = blockIdx.x * blockDim.x + threadIdx.x;
    if (n < N) deg[n] = rsqrtf(deg[n]);
}

// g1[n][k] = (sum_f x[n][f] * W1[f][k]) * dinv[n]
// block = 256 threads, 16 rows per tile, thread t -> (row t/16, col t%16)
__global__ void transform1_kernel(const float* __restrict__ x,
                                  const float* __restrict__ W1,
                                  const float* __restrict__ dinv,
                                  float* __restrict__ g1, int N) {
    __shared__ float xs[16][FIN + 4];   // pad 4 floats: banks differ across rows
    __shared__ float w[FIN][HID];
    const int t = threadIdx.x;
    for (int i = t; i < FIN * HID; i += 256) w[i / HID][i % HID] = W1[i];

    const float4* x4 = (const float4*)x;
    for (int rb = blockIdx.x * 16; rb < N; rb += gridDim.x * 16) {
        __syncthreads();  // xs reuse + (first iter) w visibility ordering below
        // load 16 rows * 128 floats = 512 float4, 2 per thread, coalesced
        for (int i = t; i < 16 * FIN / 4; i += 256) {
            int r = i >> 5;        // / (FIN/4)
            int f4 = i & 31;
            int row = rb + r;
            float4 v = (row < N) ? x4[(size_t)row * (FIN / 4) + f4]
                                 : make_float4(0.f, 0.f, 0.f, 0.f);
            *((float4*)&xs[r][f4 * 4]) = v;
        }
        __syncthreads();
        int r = t >> 4, k = t & 15;
        int row = rb + r;
        if (row < N) {
            float s = 0.f;
#pragma unroll
            for (int f = 0; f < FIN; ++f) s += xs[r][f] * w[f][k];
            g1[(size_t)row * HID + k] = s * dinv[row];
        }
    }
}

// g2[n][c] = (sum_k h[n][k] * W2[k][c]) * dinv[n]
__global__ void transform2_kernel(const float* __restrict__ h,
                                  const float* __restrict__ W2,
                                  const float* __restrict__ dinv,
                                  float* __restrict__ g2, int N) {
    int total = N * NC;
    for (int idx = blockIdx.x * blockDim.x + threadIdx.x; idx < total;
         idx += gridDim.x * blockDim.x) {
        int n = idx >> 3, c = idx & 7;
        float s = 0.f;
#pragma unroll
        for (int k = 0; k < HID; ++k) s += h[n * HID + k] * W2[k * NC + c];
        g2[idx] = s * dinv[n];
    }
}

// acc[dst[e]][k] += g[src[e]][k]
template <int FD>
__global__ void agg_kernel(const void* __restrict__ ei, int E,
                           const int* __restrict__ flag,
                           const float* __restrict__ g, float* __restrict__ acc) {
    int is64 = *flag;
    long long total = (long long)E * FD;
    long long stride = (long long)gridDim.x * blockDim.x;
    for (long long idx = (long long)blockIdx.x * blockDim.x + threadIdx.x;
         idx < total; idx += stride) {
        int e = (int)(idx / FD);
        int k = (int)(idx - (long long)e * FD);
        int s = edge_at(ei, e, is64);
        int d = edge_at(ei, (long long)E + e, is64);
        atomicAdd(&acc[(size_t)d * FD + k], g[(size_t)s * FD + k]);
    }
}

// h[n][k] = relu(dinv[n] * (acc[n][k] + g1[n][k]) + b1[k])   (in place on acc)
__global__ void finalize1_kernel(float* __restrict__ acc,
                                 const float* __restrict__ g1,
                                 const float* __restrict__ dinv,
                                 const float* __restrict__ b1, int N) {
    int total = N * HID;
    for (int idx = blockIdx.x * blockDim.x + threadIdx.x; idx < total;
         idx += gridDim.x * blockDim.x) {
        int n = idx >> 4, k = idx & 15;
        float v = dinv[n] * (acc[idx] + g1[idx]) + b1[k];
        acc[idx] = fmaxf(v, 0.f);
    }
}

// logits -> log_softmax, one thread per node (8 cols)
__global__ void finalize2_kernel(const float* __restrict__ acc2,
                                 const float* __restrict__ g2,
                                 const float* __restrict__ dinv,
                                 const float* __restrict__ b2,
                                 float* __restrict__ out, int N) {
    for (int n = blockIdx.x * blockDim.x + threadIdx.x; n < N;
         n += gridDim.x * blockDim.x) {
        float di = dinv[n];
        float logit[NC];
        float m = -1e30f;
#pragma unroll
        for (int c = 0; c < NC; ++c) {
            float v = di * (acc2[(size_t)n * NC + c] + g2[(size_t)n * NC + c]) + b2[c];
            logit[c] = v;
            m = fmaxf(m, v);
        }
        float s = 0.f;
#pragma unroll
        for (int c = 0; c < NC; ++c) s += expf(logit[c] - m);
        float lse = m + logf(s);
#pragma unroll
        for (int c = 0; c < NC; ++c) out[(size_t)n * NC + c] = logit[c] - lse;
    }
}

extern "C" void kernel_launch(void* const* d_in, const int* in_sizes, int n_in,
                              void* d_out, int out_size, void* d_ws, size_t ws_size,
                              hipStream_t stream) {
    const float* x  = (const float*)d_in[0];
    const void*  ei = d_in[1];
    const float* W1 = (const float*)d_in[2];
    const float* b1 = (const float*)d_in[3];
    const float* W2 = (const float*)d_in[4];
    const float* b2 = (const float*)d_in[5];

    const int N = in_sizes[0] / FIN;
    const int E = in_sizes[1] / 2;

    float* ws   = (float*)d_ws;
    float* deg  = ws;                          // N   (becomes dinv in place)
    float* g1   = deg + N;                     // N*HID
    float* acc1 = g1 + (size_t)N * HID;        // N*HID (becomes h in place)
    float* g2   = acc1 + (size_t)N * HID;      // N*NC
    float* acc2 = g2 + (size_t)N * NC;         // N*NC
    int*   flag = (int*)(acc2 + (size_t)N * NC);

    hipMemsetAsync(acc1, 0, (size_t)N * HID * sizeof(float), stream);
    hipMemsetAsync(acc2, 0, (size_t)N * NC * sizeof(float), stream);

    detect64_kernel<<<1, 64, 0, stream>>>(ei, E, N, flag);
    init_deg_kernel<<<(N + 255) / 256, 256, 0, stream>>>(deg, N);
    deg_kernel<<<2048, 256, 0, stream>>>(ei, E, flag, deg);
    dinv_kernel<<<(N + 255) / 256, 256, 0, stream>>>(deg, N);

    transform1_kernel<<<(N + 15) / 16, 256, 0, stream>>>(x, W1, deg, g1, N);
    agg_kernel<HID><<<4096, 256, 0, stream>>>(ei, E, flag, g1, acc1);
    finalize1_kernel<<<2048, 256, 0, stream>>>(acc1, g1, deg, b1, N);

    transform2_kernel<<<2048, 256, 0, stream>>>(acc1, W2, deg, g2, N);
    agg_kernel<NC><<<4096, 256, 0, stream>>>(ei, E, flag, g2, acc2);
    finalize2_kernel<<<(N + 255) / 256, 256, 0, stream>>>(acc2, g2, deg, b2,
                                                          (float*)d_out, N);
}